// Round 10
// baseline (272.659 us; speedup 1.0000x reference)
//
#include <hip/hip_runtime.h>

// Problem constants
#define B_  64
#define T_  2048
#define X_  256

// scan chunking: emit length L and warmup W (||A^16|| ~ 3e-4 << bf16 noise)
#define SCAN_L 16
#define SCAN_W 16

// heads: timesteps per persistent block (grid = 2 heads x (T_/HEADS_TCH))
#define HEADS_TCH 8
// drive: timesteps per persistent block (grid = T_/DRIVE_TCH)
#define DRIVE_TCH 4

typedef __bf16 bf16x8 __attribute__((ext_vector_type(8)));
typedef float  f32x4  __attribute__((ext_vector_type(4)));

__device__ __forceinline__ unsigned short f2bf(float v) {
  unsigned int x = __float_as_uint(v);
  x += 0x7fffu + ((x >> 16) & 1u);   // RNE
  return (unsigned short)(x >> 16);
}
__device__ __forceinline__ float bf2f(unsigned short s) {
  return __uint_as_float(((unsigned int)s) << 16);
}
__device__ __forceinline__ unsigned int pack2(float a, float b) {
  return (unsigned int)f2bf(a) | ((unsigned int)f2bf(b) << 16);
}

// LDS-only barrier: waits lgkm only (no vmcnt(0) drain of in-flight global
// ops at every barrier; global loads are register-consumed with counted
// vmcnt at the use).
__device__ __forceinline__ void bar_lds() {
  asm volatile("s_waitcnt lgkmcnt(0)\n\ts_barrier" ::: "memory");
}

// ---------------------------------------------------------------------------
// Kernel 1 (merged): head weights fp32->bf16 (blocks 0..591) and
// wcat[256][96]=[K_w|Bm_w] bf16 + bsum=K_b+Bm_b+A_b (blocks 592..687).
// ---------------------------------------------------------------------------
__global__ __launch_bounds__(256) void conv_kernel(
    const float* __restrict__ cy1, const float* __restrict__ cy2,
    const float* __restrict__ cz1, const float* __restrict__ cz2,
    const float* __restrict__ Kw, const float* __restrict__ Bw,
    const float* __restrict__ Kb, const float* __restrict__ Bb,
    const float* __restrict__ Ab,
    unsigned short* __restrict__ wb,
    unsigned short* __restrict__ wcat, float* __restrict__ bsum) {
  if (blockIdx.x < 592) {
    int i = blockIdx.x * 256 + threadIdx.x;
    if (i < 65536)        wb[i] = f2bf(cy1[i]);
    else if (i < 81920)   wb[i] = f2bf(cy2[i - 65536]);
    else if (i < 147456)  wb[i] = f2bf(cz1[i - 81920]);
    else if (i < 151552)  wb[i] = f2bf(cz2[i - 147456]);
  } else {
    int k = blockIdx.x - 592;   // 0..95
    int x = threadIdx.x;        // 0..255
    float v = (k < 64) ? Kw[x * 64 + k] : Bw[x * 32 + (k - 64)];
    wcat[x * 96 + k] = f2bf(v);
    if (k == 0) bsum[x] = Kb[x] + Bb[x] + Ab[x];
  }
}

// ---------------------------------------------------------------------------
// Kernel 2 v2: weight-stationary drive (measured clean in r8).
// ---------------------------------------------------------------------------
__global__ __launch_bounds__(512, 4) void drive_kernel(
    const float* __restrict__ y, const float* __restrict__ u,
    const unsigned short* __restrict__ wcat, const float* __restrict__ bsum,
    unsigned short* __restrict__ drv) {
  __shared__ __align__(16) unsigned short cat[64 * 104];  // 96 + 8 pad
  __shared__ __align__(16) unsigned short ot[64 * 264];
  const int tid = threadIdx.x;
  const int t0  = blockIdx.x * DRIVE_TCH;
  const int wv = tid >> 6, lane = tid & 63, lm = lane & 15, quad = lane >> 4;

  // weight fragments: wave owns n-cols [wv*32, wv*32+32), loaded once
  bf16x8 bf[2][3];
  float  bias[2];
#pragma unroll
  for (int nt = 0; nt < 2; nt++) {
    int n = wv * 32 + nt * 16 + lm;
#pragma unroll
    for (int kk = 0; kk < 3; kk++)
      bf[nt][kk] = *(const bf16x8*)(wcat + (size_t)n * 96 + kk * 32 + quad * 8);
    bias[nt] = bsum[n];
  }

  for (int j = 0; j < DRIVE_TCH; j++) {
    const int t = t0 + j;

    // stage y: 64 rows x 16 float4 chunks = 1024 (2 per thread)
#pragma unroll
    for (int it = 0; it < 2; it++) {
      int ch = it * 512 + tid;
      int row = ch >> 4, c4 = (ch & 15) * 4;
      float4 v = *(const float4*)(y + ((size_t)row * T_ + t) * 64 + c4);
      uint2 pv; pv.x = pack2(v.x, v.y); pv.y = pack2(v.z, v.w);
      *(uint2*)(cat + row * 104 + c4) = pv;
    }
    // stage u: 64 rows x 8 float4 chunks = 512 (1 per thread)
    {
      int ch = tid;
      int row = ch >> 3, c4 = (ch & 7) * 4;
      float4 v = *(const float4*)(u + ((size_t)row * T_ + t) * 32 + c4);
      uint2 pv; pv.x = pack2(v.x, v.y); pv.y = pack2(v.z, v.w);
      *(uint2*)(cat + row * 104 + 64 + c4) = pv;
    }
    bar_lds();   // cat ready; also guards ot reuse (store of t-1 read pre-bar)

    f32x4 acc[2][4];   // [nt][m]
#pragma unroll
    for (int nt = 0; nt < 2; nt++)
#pragma unroll
      for (int m = 0; m < 4; m++) acc[nt][m] = (f32x4){0.f, 0.f, 0.f, 0.f};

#pragma unroll
    for (int m = 0; m < 4; m++) {
      bf16x8 af[3];
#pragma unroll
      for (int kk = 0; kk < 3; kk++)
        af[kk] = *(const bf16x8*)(cat + (m * 16 + lm) * 104 + kk * 32 + quad * 8);
#pragma unroll
      for (int kk = 0; kk < 3; kk++)
#pragma unroll
        for (int nt = 0; nt < 2; nt++)
          acc[nt][m] = __builtin_amdgcn_mfma_f32_16x16x32_bf16(af[kk], bf[nt][kk], acc[nt][m], 0, 0, 0);
    }

    // epilogue: bias -> ot (wave writes its own 32 cols)
#pragma unroll
    for (int nt = 0; nt < 2; nt++) {
      int n = wv * 32 + nt * 16 + lm;
#pragma unroll
      for (int m = 0; m < 4; m++)
#pragma unroll
        for (int rg = 0; rg < 4; rg++)
          ot[(m * 16 + quad * 4 + rg) * 264 + n] = f2bf(acc[nt][m][rg] + bias[nt]);
    }
    bar_lds();   // all cat reads + ot writes done

    // store ot -> drv (coalesced): 64 rows x 32 uint4 chunks = 2048 (4/thread)
#pragma unroll
    for (int it = 0; it < 4; it++) {
      int ch = it * 512 + tid, row = ch >> 5, col = (ch & 31) * 8;
      uint4 v = *(const uint4*)(ot + row * 264 + col);
      *(uint4*)(drv + ((size_t)t * B_ + row) * X_ + col) = v;
    }
    // next iteration's stage-bar covers ot-read completion before epi rewrite
  }
}

// ---------------------------------------------------------------------------
// Kernel 3 v4: 8-wave scan, 32 X-cols/wave, zero-cost in-step emit.
//   r9 falsifier: 2-deep prefetch was ~null -> scan is NOT HBM-bound; it is
//   the per-step serial chain x 32 steps with only 8 waves/CU of overlap.
//   Fix: double resident waves WITHOUT crossing the 128-reg cliff.
//   - wave owns 32 output cols: w[2][8] = 64 VGPR (v7-verified mapping).
//   - emit restructured to ZERO extra pressure: wave wv's emit slice is
//     exactly bfr[wv]; the store issues INSIDE the unrolled bfr-read loop at
//     kk==wv (wave-uniform test), consuming a value that is live anyway.
//     No switch, no carried em-state (v7's spill cause), no final flush.
//   - regs ~115-125 <= 128 -> (512,4) -> 4 waves/SIMD -> 2 independent
//     8-wave blocks/CU = 16 waves/CU (2x r9). Grid 512 = exactly 2/CU.
//   Emitted values = identical Xb contents; repack/d-add order unchanged ->
//   bit-identical outputs.
//   Falsifiers: VGPR>128 or WRITE>>65.5MB = spill -> revert to r9 scan;
//   clean but dur flat -> chain-bound -> A^2-stride-2 next.
// ---------------------------------------------------------------------------
__global__ __launch_bounds__(512, 4) void scan_kernel(
    const unsigned short* __restrict__ drv,   // d' = drive + A_b
    const float* __restrict__ Aw,
    unsigned short* __restrict__ xs) {
  __shared__ __align__(16) unsigned short Xb[2][16 * 264];
  const int tid = threadIdx.x;
  const int wv = tid >> 6, lane = tid & 63, lm = lane & 15, quad = lane >> 4;
  const int c  = blockIdx.x >> 2;            // chunk 0..127
  const int b0 = (blockIdx.x & 3) * 16;

  union U8 { bf16x8 v; unsigned short u[8]; uint4 q; };
  // wave wv owns output X-cols [wv*32, wv*32+32): A rows (wv*2+mt)*16+lm
  bf16x8 w[2][8];
#pragma unroll
  for (int mt = 0; mt < 2; mt++) {
#pragma unroll
    for (int kk = 0; kk < 8; kk++) {
      const float* p = Aw + (size_t)((wv * 2 + mt) * 16 + lm) * 256 + kk * 32 + quad * 8;
      float4 a = *(const float4*)p;
      float4 b = *(const float4*)(p + 4);
      U8 tmp;
      tmp.u[0] = f2bf(a.x); tmp.u[1] = f2bf(a.y); tmp.u[2] = f2bf(a.z); tmp.u[3] = f2bf(a.w);
      tmp.u[4] = f2bf(b.x); tmp.u[5] = f2bf(b.y); tmp.u[6] = f2bf(b.z); tmp.u[7] = f2bf(b.w);
      w[mt][kk] = tmp.v;
    }
  }

  {
    unsigned int* xz = (unsigned int*)&Xb[0][0];
    for (int i = tid; i < (16 * 264) / 2; i += 512) xz[i] = 0u;
  }
  bar_lds();

  const int j0 = (c == 0) ? SCAN_W : 0;      // chunk 0 starts exactly at t=0
  int t = c * SCAN_L - SCAN_W + j0;

  uint2 dcur[2];
  {
    const unsigned short* dp = drv + ((size_t)t * B_ + b0 + lm) * X_ + wv * 32 + quad * 4;
    dcur[0] = *(const uint2*)(dp);
    dcur[1] = *(const uint2*)(dp + 16);
  }

  int p = 0;
  for (int j = j0; j < SCAN_W + SCAN_L; j++, t++) {
    uint2 dnext[2];
    {
      int tn = (t + 1 < T_) ? t + 1 : T_ - 1;
      const unsigned short* dp = drv + ((size_t)tn * B_ + b0 + lm) * X_ + wv * 32 + quad * 4;
      dnext[0] = *(const uint2*)(dp);
      dnext[1] = *(const uint2*)(dp + 16);
    }

    const bool doemit = (j >= SCAN_W);
    bf16x8 bfr[8];
    {
      const unsigned short* xb = &Xb[p][0] + lm * 264;
#pragma unroll
      for (int kk = 0; kk < 8; kk++) {
        bfr[kk] = *(const bf16x8*)(xb + kk * 32 + quad * 8);
        if (doemit && kk == wv) {   // wave-uniform; value live anyway
          U8 cc; cc.v = bfr[kk];
          *(uint4*)(xs + ((size_t)t * B_ + b0 + lm) * X_ + wv * 32 + quad * 8) = cc.q;
        }
      }
    }

    f32x4 acc[2];
    acc[0] = (f32x4){0.f, 0.f, 0.f, 0.f};
    acc[1] = (f32x4){0.f, 0.f, 0.f, 0.f};
#pragma unroll
    for (int kk = 0; kk < 8; kk++) {
      acc[0] = __builtin_amdgcn_mfma_f32_16x16x32_bf16(w[0][kk], bfr[kk], acc[0], 0, 0, 0);
      acc[1] = __builtin_amdgcn_mfma_f32_16x16x32_bf16(w[1][kk], bfr[kk], acc[1], 0, 0, 0);
    }

    {
      unsigned short* xn = &Xb[1 - p][0] + lm * 264 + wv * 32 + quad * 4;
#pragma unroll
      for (int mt = 0; mt < 2; mt++) {
        unsigned int lo = dcur[mt].x, hi = dcur[mt].y;
        float d0 = bf2f((unsigned short)(lo & 0xffff));
        float d1 = bf2f((unsigned short)(lo >> 16));
        float d2 = bf2f((unsigned short)(hi & 0xffff));
        float d3 = bf2f((unsigned short)(hi >> 16));
        uint2 ov;
        ov.x = pack2(acc[mt][0] + d0, acc[mt][1] + d1);
        ov.y = pack2(acc[mt][2] + d2, acc[mt][3] + d3);
        *(uint2*)(xn + mt * 16) = ov;
      }
    }
    dcur[0] = dnext[0];
    dcur[1] = dnext[1];
    bar_lds();
    p ^= 1;
  }
}

// ---------------------------------------------------------------------------
// Kernel 4 v6: weight-stationary heads, spill-proof (measured clean in r6).
// ---------------------------------------------------------------------------
__global__ __launch_bounds__(512, 4) void heads_kernel(
    const unsigned short* __restrict__ xs, const unsigned short* __restrict__ wb,
    const float* __restrict__ by1, const float* __restrict__ by2,
    const float* __restrict__ bz1, const float* __restrict__ bz2,
    float* __restrict__ yout, float* __restrict__ zout) {
  __shared__ __align__(16) unsigned short sbuf[64 * 264];   // xt, then ht
  __shared__ __align__(16) unsigned short w2s[64 * 264];    // W2 rows (64 or 16)
  const int tid  = threadIdx.x;
  const int head = blockIdx.x & 1;
  const int t0   = (blockIdx.x >> 1) * HEADS_TCH;

  const int wv = tid >> 6, lane = tid & 63, lm = lane & 15, quad = lane >> 4;
  const unsigned short* w1 = wb + (head ? 81920  : 0);
  const unsigned short* w2 = wb + (head ? 147456 : 65536);
  const float* b1p = head ? bz1 : by1;
  const float* b2p = head ? bz2 : by2;

  // ---- stage W2 into LDS once per block (covered by first P0 barrier) ----
  {
    const int nrow = head ? 16 : 64;
    for (int ch = tid; ch < nrow * 32; ch += 512) {
      int row = ch >> 5, col = (ch & 31) * 8;
      *(uint4*)(w2s + row * 264 + col) = *(const uint4*)(w2 + (size_t)row * 256 + col);
    }
  }

  // ---- W1 fragments, loaded ONCE per block (wave owns n-cols [wv*32,+32)) ----
  bf16x8 w1f[2][8];
  float  bias1[2];
#pragma unroll
  for (int nt = 0; nt < 2; nt++) {
    int n = wv * 32 + nt * 16 + lm;
#pragma unroll
    for (int kk = 0; kk < 8; kk++)
      w1f[nt][kk] = *(const bf16x8*)(w1 + (size_t)n * 256 + kk * 32 + quad * 8);
    bias1[nt] = b1p[n];
  }
  // layer-2 tile assignment: head0: wave -> (ntile = wv&3, mpair = wv>>2);
  // head1: waves 0-3, m-tile = wv.
  const int ntile = head ? 0 : (wv & 3);
  const int mpair = head ? 0 : (wv >> 2);
  float bias2 = 0.f;
  if (head == 0 || wv < 4) bias2 = b2p[ntile * 16 + lm];

  // ---- x stage mapping: 64 rows x 32 uint4-chunks, 4 chunks/thread ----
  const int srow = tid >> 5;          // 0..15 (+ c*16)
  const int scol = (tid & 31) * 8;    // bf16 col

  for (int j = 0; j < HEADS_TCH; j++) {
    const int t = t0 + j;

    // P0: direct global -> LDS stage of x_t (short-lived temps, NO
    // loop-carried prefetch state -> nothing for the allocator to spill)
    {
      uint4 x0 = *(const uint4*)(xs + ((size_t)t * 64 + srow +  0) * 256 + scol);
      uint4 x1 = *(const uint4*)(xs + ((size_t)t * 64 + srow + 16) * 256 + scol);
      uint4 x2 = *(const uint4*)(xs + ((size_t)t * 64 + srow + 32) * 256 + scol);
      uint4 x3 = *(const uint4*)(xs + ((size_t)t * 64 + srow + 48) * 256 + scol);
      *(uint4*)(sbuf + (srow +  0) * 264 + scol) = x0;
      *(uint4*)(sbuf + (srow + 16) * 264 + scol) = x1;
      *(uint4*)(sbuf + (srow + 32) * 264 + scol) = x2;
      *(uint4*)(sbuf + (srow + 48) * 264 + scol) = x3;
    }
    bar_lds();

    // P1: layer 1  h = x @ W1^T (wave's 32 n-cols, all 64 rows), kk-outer:
    // 8 independent acc targets per kk -> no dependent-MFMA chains.
    f32x4 acc[2][4];   // [nt][m]
#pragma unroll
    for (int nt = 0; nt < 2; nt++)
#pragma unroll
      for (int m = 0; m < 4; m++) acc[nt][m] = (f32x4){0.f, 0.f, 0.f, 0.f};

#pragma unroll
    for (int kk = 0; kk < 8; kk++) {
      bf16x8 af[4];
#pragma unroll
      for (int m = 0; m < 4; m++)
        af[m] = *(const bf16x8*)(sbuf + (m * 16 + lm) * 264 + kk * 32 + quad * 8);
#pragma unroll
      for (int nt = 0; nt < 2; nt++)
#pragma unroll
        for (int m = 0; m < 4; m++)
          acc[nt][m] = __builtin_amdgcn_mfma_f32_16x16x32_bf16(af[m], w1f[nt][kk], acc[nt][m], 0, 0, 0);
    }
    bar_lds();   // all waves done READING xt -> safe to overwrite with h

    // P2: epilogue bias+relu -> sbuf (now ht)
#pragma unroll
    for (int nt = 0; nt < 2; nt++) {
      int n = wv * 32 + nt * 16 + lm;
#pragma unroll
      for (int m = 0; m < 4; m++)
#pragma unroll
        for (int rg = 0; rg < 4; rg++) {
          float v = fmaxf(acc[nt][m][rg] + bias1[nt], 0.f);
          sbuf[(m * 16 + quad * 4 + rg) * 264 + n] = f2bf(v);
        }
    }
    bar_lds();   // layer2 reads all cols of ht

    // P3: layer 2 + sigmoid + store (W2 fragments read from LDS)
    if (head == 0) {       // N=64: wave -> n-tile (wv&3), m-tiles {2*mpair,2*mpair+1}
      f32x4 a2[2];
#pragma unroll
      for (int mm = 0; mm < 2; mm++) a2[mm] = (f32x4){0.f, 0.f, 0.f, 0.f};
#pragma unroll
      for (int kk = 0; kk < 8; kk++) {
        bf16x8 b = *(const bf16x8*)(w2s + (ntile * 16 + lm) * 264 + kk * 32 + quad * 8);
#pragma unroll
        for (int mm = 0; mm < 2; mm++) {
          int m = mpair * 2 + mm;
          bf16x8 a = *(const bf16x8*)(sbuf + (m * 16 + lm) * 264 + kk * 32 + quad * 8);
          a2[mm] = __builtin_amdgcn_mfma_f32_16x16x32_bf16(a, b, a2[mm], 0, 0, 0);
        }
      }
      int n = ntile * 16 + lm;
#pragma unroll
      for (int mm = 0; mm < 2; mm++)
#pragma unroll
        for (int rg = 0; rg < 4; rg++) {
          int bb = (mpair * 2 + mm) * 16 + quad * 4 + rg;
          float v = a2[mm][rg] + bias2;
          v = 1.f / (1.f + __expf(-v));
          yout[((size_t)bb * T_ + t) * 64 + n] = v;
        }
    } else if (wv < 4) {   // N=16: waves 0-3 take m-tile = wv
      f32x4 a2 = (f32x4){0.f, 0.f, 0.f, 0.f};
#pragma unroll
      for (int kk = 0; kk < 8; kk++) {
        bf16x8 b = *(const bf16x8*)(w2s + lm * 264 + kk * 32 + quad * 8);
        bf16x8 a = *(const bf16x8*)(sbuf + (wv * 16 + lm) * 264 + kk * 32 + quad * 8);
        a2 = __builtin_amdgcn_mfma_f32_16x16x32_bf16(a, b, a2, 0, 0, 0);
      }
#pragma unroll
      for (int rg = 0; rg < 4; rg++) {
        int bb = wv * 16 + quad * 4 + rg;
        float v = a2[rg] + bias2;
        v = 1.f / (1.f + __expf(-v));
        zout[((size_t)bb * T_ + t) * 16 + lm] = v;
      }
    }
    bar_lds();   // h reads done -> next P0 may overwrite sbuf
  }
}

// ---------------------------------------------------------------------------
extern "C" void kernel_launch(void* const* d_in, const int* in_sizes, int n_in,
                              void* d_out, int out_size, void* d_ws, size_t ws_size,
                              hipStream_t stream) {
  const float* y    = (const float*)d_in[0];
  const float* u    = (const float*)d_in[1];
  const float* Aw   = (const float*)d_in[2];
  const float* Ab   = (const float*)d_in[3];
  const float* Kw   = (const float*)d_in[4];
  const float* Kb   = (const float*)d_in[5];
  const float* Bw   = (const float*)d_in[6];
  const float* Bb   = (const float*)d_in[7];
  const float* Cy1w = (const float*)d_in[8];
  const float* Cy1b = (const float*)d_in[9];
  const float* Cy2w = (const float*)d_in[10];
  const float* Cy2b = (const float*)d_in[11];
  const float* Cz1w = (const float*)d_in[12];
  const float* Cz1b = (const float*)d_in[13];
  const float* Cz2w = (const float*)d_in[14];
  const float* Cz2b = (const float*)d_in[15];

  // ws layout (bf16 unless noted):
  //   drv [T*B*X] | xs [T*B*X] | wb [151552] | wcat [24576] | bsum fp32 [256]
  unsigned short* drv  = (unsigned short*)d_ws;
  unsigned short* xs   = drv + (size_t)T_ * B_ * X_;
  unsigned short* wb   = xs  + (size_t)T_ * B_ * X_;
  unsigned short* wcat = wb + 151552;
  float*          bsum = (float*)(wcat + 24576);

  float* yout = (float*)d_out;
  float* zout = yout + (size_t)B_ * T_ * 64;

  hipLaunchKernelGGL(conv_kernel, dim3(688), dim3(256), 0, stream,
                     Cy1w, Cy2w, Cz1w, Cz2w, Kw, Bw, Kb, Bb, Ab, wb, wcat, bsum);
  hipLaunchKernelGGL(drive_kernel, dim3(T_ / DRIVE_TCH), dim3(512), 0, stream,
                     y, u, wcat, bsum, drv);
  hipLaunchKernelGGL(scan_kernel, dim3((T_ / SCAN_L) * 4), dim3(512), 0, stream,
                     drv, Aw, xs);
  hipLaunchKernelGGL(heads_kernel, dim3(2 * (T_ / HEADS_TCH)), dim3(512), 0, stream,
                     xs, wb, Cy1b, Cy2b, Cz1b, Cz2b, yout, zout);
}

// Round 11
// 260.385 us; speedup vs baseline: 1.0471x; 1.0471x over previous
//
#include <hip/hip_runtime.h>

// Problem constants
#define B_  64
#define T_  2048
#define X_  256

// scan chunking: emit length L and warmup W (||A^16|| ~ 3e-4 << bf16 noise)
#define SCAN_L 16
#define SCAN_W 16

// heads: timesteps per persistent block (grid = 2 heads x (T_/HEADS_TCH))
#define HEADS_TCH 8
// drive: timesteps per persistent block (grid = T_/DRIVE_TCH)
#define DRIVE_TCH 4

typedef __bf16 bf16x8 __attribute__((ext_vector_type(8)));
typedef float  f32x4  __attribute__((ext_vector_type(4)));

__device__ __forceinline__ unsigned short f2bf(float v) {
  unsigned int x = __float_as_uint(v);
  x += 0x7fffu + ((x >> 16) & 1u);   // RNE
  return (unsigned short)(x >> 16);
}
__device__ __forceinline__ float bf2f(unsigned short s) {
  return __uint_as_float(((unsigned int)s) << 16);
}
__device__ __forceinline__ unsigned int pack2(float a, float b) {
  return (unsigned int)f2bf(a) | ((unsigned int)f2bf(b) << 16);
}

// LDS-only barrier: waits lgkm only (no vmcnt(0) drain of in-flight global
// ops at every barrier; global loads are register-consumed with counted
// vmcnt at the use).
__device__ __forceinline__ void bar_lds() {
  asm volatile("s_waitcnt lgkmcnt(0)\n\ts_barrier" ::: "memory");
}

// ---------------------------------------------------------------------------
// Kernel 1 (merged): head weights fp32->bf16 (blocks 0..591) and
// wcat[256][96]=[K_w|Bm_w] bf16 + bsum=K_b+Bm_b+A_b (blocks 592..687).
// ---------------------------------------------------------------------------
__global__ __launch_bounds__(256) void conv_kernel(
    const float* __restrict__ cy1, const float* __restrict__ cy2,
    const float* __restrict__ cz1, const float* __restrict__ cz2,
    const float* __restrict__ Kw, const float* __restrict__ Bw,
    const float* __restrict__ Kb, const float* __restrict__ Bb,
    const float* __restrict__ Ab,
    unsigned short* __restrict__ wb,
    unsigned short* __restrict__ wcat, float* __restrict__ bsum) {
  if (blockIdx.x < 592) {
    int i = blockIdx.x * 256 + threadIdx.x;
    if (i < 65536)        wb[i] = f2bf(cy1[i]);
    else if (i < 81920)   wb[i] = f2bf(cy2[i - 65536]);
    else if (i < 147456)  wb[i] = f2bf(cz1[i - 81920]);
    else if (i < 151552)  wb[i] = f2bf(cz2[i - 147456]);
  } else {
    int k = blockIdx.x - 592;   // 0..95
    int x = threadIdx.x;        // 0..255
    float v = (k < 64) ? Kw[x * 64 + k] : Bw[x * 32 + (k - 64)];
    wcat[x * 96 + k] = f2bf(v);
    if (k == 0) bsum[x] = Kb[x] + Bb[x] + Ab[x];
  }
}

// ---------------------------------------------------------------------------
// Kernel 2 v2: weight-stationary drive (measured clean in r8).
// ---------------------------------------------------------------------------
__global__ __launch_bounds__(512, 4) void drive_kernel(
    const float* __restrict__ y, const float* __restrict__ u,
    const unsigned short* __restrict__ wcat, const float* __restrict__ bsum,
    unsigned short* __restrict__ drv) {
  __shared__ __align__(16) unsigned short cat[64 * 104];  // 96 + 8 pad
  __shared__ __align__(16) unsigned short ot[64 * 264];
  const int tid = threadIdx.x;
  const int t0  = blockIdx.x * DRIVE_TCH;
  const int wv = tid >> 6, lane = tid & 63, lm = lane & 15, quad = lane >> 4;

  // weight fragments: wave owns n-cols [wv*32, wv*32+32), loaded once
  bf16x8 bf[2][3];
  float  bias[2];
#pragma unroll
  for (int nt = 0; nt < 2; nt++) {
    int n = wv * 32 + nt * 16 + lm;
#pragma unroll
    for (int kk = 0; kk < 3; kk++)
      bf[nt][kk] = *(const bf16x8*)(wcat + (size_t)n * 96 + kk * 32 + quad * 8);
    bias[nt] = bsum[n];
  }

  for (int j = 0; j < DRIVE_TCH; j++) {
    const int t = t0 + j;

    // stage y: 64 rows x 16 float4 chunks = 1024 (2 per thread)
#pragma unroll
    for (int it = 0; it < 2; it++) {
      int ch = it * 512 + tid;
      int row = ch >> 4, c4 = (ch & 15) * 4;
      float4 v = *(const float4*)(y + ((size_t)row * T_ + t) * 64 + c4);
      uint2 pv; pv.x = pack2(v.x, v.y); pv.y = pack2(v.z, v.w);
      *(uint2*)(cat + row * 104 + c4) = pv;
    }
    // stage u: 64 rows x 8 float4 chunks = 512 (1 per thread)
    {
      int ch = tid;
      int row = ch >> 3, c4 = (ch & 7) * 4;
      float4 v = *(const float4*)(u + ((size_t)row * T_ + t) * 32 + c4);
      uint2 pv; pv.x = pack2(v.x, v.y); pv.y = pack2(v.z, v.w);
      *(uint2*)(cat + row * 104 + 64 + c4) = pv;
    }
    bar_lds();   // cat ready; also guards ot reuse (store of t-1 read pre-bar)

    f32x4 acc[2][4];   // [nt][m]
#pragma unroll
    for (int nt = 0; nt < 2; nt++)
#pragma unroll
      for (int m = 0; m < 4; m++) acc[nt][m] = (f32x4){0.f, 0.f, 0.f, 0.f};

#pragma unroll
    for (int m = 0; m < 4; m++) {
      bf16x8 af[3];
#pragma unroll
      for (int kk = 0; kk < 3; kk++)
        af[kk] = *(const bf16x8*)(cat + (m * 16 + lm) * 104 + kk * 32 + quad * 8);
#pragma unroll
      for (int kk = 0; kk < 3; kk++)
#pragma unroll
        for (int nt = 0; nt < 2; nt++)
          acc[nt][m] = __builtin_amdgcn_mfma_f32_16x16x32_bf16(af[kk], bf[nt][kk], acc[nt][m], 0, 0, 0);
    }

    // epilogue: bias -> ot (wave writes its own 32 cols)
#pragma unroll
    for (int nt = 0; nt < 2; nt++) {
      int n = wv * 32 + nt * 16 + lm;
#pragma unroll
      for (int m = 0; m < 4; m++)
#pragma unroll
        for (int rg = 0; rg < 4; rg++)
          ot[(m * 16 + quad * 4 + rg) * 264 + n] = f2bf(acc[nt][m][rg] + bias[nt]);
    }
    bar_lds();   // all cat reads + ot writes done

    // store ot -> drv (coalesced): 64 rows x 32 uint4 chunks = 2048 (4/thread)
#pragma unroll
    for (int it = 0; it < 4; it++) {
      int ch = it * 512 + tid, row = ch >> 5, col = (ch & 31) * 8;
      uint4 v = *(const uint4*)(ot + row * 264 + col);
      *(uint4*)(drv + ((size_t)t * B_ + row) * X_ + col) = v;
    }
    // next iteration's stage-bar covers ot-read completion before epi rewrite
  }
}

// ---------------------------------------------------------------------------
// Kernel 3 v5: dual-chain interleaved scan (fat-register, spill-proof).
//   Post-mortems: 4-wave/SIMD attempts spilled twice (v7, v10: demand >128);
//   deeper HBM prefetch null (v9). Remaining lever is ILP in the fat-register
//   regime. One 256-thread block runs TWO independent chains (chunks c and
//   c+64, same b-group) interleaved per step:
//   - A fragments w[4][8] (128 VGPR) loaded ONCE, shared by both chains.
//   - per super-step: chain1 {ds_read, 32 MFMA, repack, ds_write} then
//     chain2 (no deps -> compiler interleaves; chain2 fills chain1's
//     latency bubbles). ONE barrier per 2 chain-steps (was 1 per step).
//   - grid 256 = 1 block/CU; __launch_bounds__(256,1) -> allocator can use
//     up to 512 VGPR -> ~270-reg demand CANNOT spill (no-spill through 450).
//   - per-chain math is byte-for-byte the v6 step (immediate emit from live
//     bfr, same repack order) -> bit-identical outputs.
//   Falsifier: WRITE_SIZE must stay 65.5 MB. Clean but dur >= 74 us ->
//   ILP doesn't substitute for TLP -> revert to r9 scan.
// ---------------------------------------------------------------------------
__global__ __launch_bounds__(256, 1) void scan_kernel(
    const unsigned short* __restrict__ drv,   // d' = drive + A_b
    const float* __restrict__ Aw,
    unsigned short* __restrict__ xs) {
  __shared__ __align__(16) unsigned short Xb[2][2][16 * 264];  // [chain][pingpong]
  const int tid = threadIdx.x;
  const int wv = tid >> 6, lane = tid & 63, lm = lane & 15, quad = lane >> 4;
  const int pr = blockIdx.x >> 2;                 // pair 0..63
  const int b0 = (blockIdx.x & 3) * 16;
  const int c1 = pr;                              // chunk 0..63
  const int c2 = pr + (T_ / SCAN_L / 2);          // chunk 64..127

  union U8 { bf16x8 v; unsigned short u[8]; uint4 q; };
  bf16x8 w[4][8];   // wave owns A-rows [wv*64, wv*64+64), shared by chains
#pragma unroll
  for (int mt = 0; mt < 4; mt++) {
#pragma unroll
    for (int kk = 0; kk < 8; kk++) {
      const float* p = Aw + (size_t)((wv * 4 + mt) * 16 + lm) * 256 + kk * 32 + quad * 8;
      float4 a = *(const float4*)p;
      float4 b = *(const float4*)(p + 4);
      U8 tmp;
      tmp.u[0] = f2bf(a.x); tmp.u[1] = f2bf(a.y); tmp.u[2] = f2bf(a.z); tmp.u[3] = f2bf(a.w);
      tmp.u[4] = f2bf(b.x); tmp.u[5] = f2bf(b.y); tmp.u[6] = f2bf(b.z); tmp.u[7] = f2bf(b.w);
      w[mt][kk] = tmp.v;
    }
  }

  {  // zero all state buffers
    unsigned int* xz = (unsigned int*)&Xb[0][0][0];
    for (int i = tid; i < (2 * 2 * 16 * 264) / 2; i += 256) xz[i] = 0u;
  }
  bar_lds();

  int t1 = (c1 == 0) ? 0 : (c1 * SCAN_L - SCAN_W);
  int t2 = c2 * SCAN_L - SCAN_W;

  uint2 d1[4], d2[4];
  {
    const unsigned short* dp = drv + ((size_t)t1 * B_ + b0 + lm) * X_ + wv * 64 + quad * 4;
#pragma unroll
    for (int mt = 0; mt < 4; mt++) d1[mt] = *(const uint2*)(dp + mt * 16);
  }
  {
    const unsigned short* dp = drv + ((size_t)t2 * B_ + b0 + lm) * X_ + wv * 64 + quad * 4;
#pragma unroll
    for (int mt = 0; mt < 4; mt++) d2[mt] = *(const uint2*)(dp + mt * 16);
  }

  int p1 = 0, p2 = 0;
  for (int j = 0; j < SCAN_W + SCAN_L; j++) {
    const bool act1 = (c1 > 0) || (j >= SCAN_W);  // c1==0 has no warmup
    const bool em   = (j >= SCAN_W);

    // ---------------- chain 1 ----------------
    if (act1) {
      uint2 dn[4];
      {
        int tn = (t1 + 1 < T_) ? t1 + 1 : T_ - 1;
        const unsigned short* dp = drv + ((size_t)tn * B_ + b0 + lm) * X_ + wv * 64 + quad * 4;
#pragma unroll
        for (int mt = 0; mt < 4; mt++) dn[mt] = *(const uint2*)(dp + mt * 16);
      }
      bf16x8 bfr[8];
      {
        const unsigned short* xb = &Xb[0][p1][0] + lm * 264;
#pragma unroll
        for (int kk = 0; kk < 8; kk++)
          bfr[kk] = *(const bf16x8*)(xb + kk * 32 + quad * 8);
      }
      f32x4 acc[4];
#pragma unroll
      for (int mt = 0; mt < 4; mt++) acc[mt] = (f32x4){0.f, 0.f, 0.f, 0.f};
#pragma unroll
      for (int kk = 0; kk < 8; kk++)
#pragma unroll
        for (int mt = 0; mt < 4; mt++)
          acc[mt] = __builtin_amdgcn_mfma_f32_16x16x32_bf16(w[mt][kk], bfr[kk], acc[mt], 0, 0, 0);
      if (em) {   // immediate emit of pre-update x_t (bfr is live anyway)
        unsigned short* ep = xs + ((size_t)t1 * B_ + b0 + lm) * X_ + quad * 8;
        U8 e0, e1;
        e0.v = (wv == 0) ? bfr[0] : (wv == 1) ? bfr[2] : (wv == 2) ? bfr[4] : bfr[6];
        e1.v = (wv == 0) ? bfr[1] : (wv == 1) ? bfr[3] : (wv == 2) ? bfr[5] : bfr[7];
        *(uint4*)(ep + (2 * wv) * 32)     = e0.q;
        *(uint4*)(ep + (2 * wv + 1) * 32) = e1.q;
      }
      {
        unsigned short* xn = &Xb[0][1 - p1][0] + lm * 264 + wv * 64 + quad * 4;
#pragma unroll
        for (int mt = 0; mt < 4; mt++) {
          unsigned int lo = d1[mt].x, hi = d1[mt].y;
          float f0 = bf2f((unsigned short)(lo & 0xffff));
          float f1 = bf2f((unsigned short)(lo >> 16));
          float f2 = bf2f((unsigned short)(hi & 0xffff));
          float f3 = bf2f((unsigned short)(hi >> 16));
          uint2 ov;
          ov.x = pack2(acc[mt][0] + f0, acc[mt][1] + f1);
          ov.y = pack2(acc[mt][2] + f2, acc[mt][3] + f3);
          *(uint2*)(xn + mt * 16) = ov;
        }
      }
#pragma unroll
      for (int mt = 0; mt < 4; mt++) d1[mt] = dn[mt];
      t1++; p1 ^= 1;
    }

    // ---------------- chain 2 (always active) ----------------
    {
      uint2 dn[4];
      {
        int tn = (t2 + 1 < T_) ? t2 + 1 : T_ - 1;
        const unsigned short* dp = drv + ((size_t)tn * B_ + b0 + lm) * X_ + wv * 64 + quad * 4;
#pragma unroll
        for (int mt = 0; mt < 4; mt++) dn[mt] = *(const uint2*)(dp + mt * 16);
      }
      bf16x8 bfr[8];
      {
        const unsigned short* xb = &Xb[1][p2][0] + lm * 264;
#pragma unroll
        for (int kk = 0; kk < 8; kk++)
          bfr[kk] = *(const bf16x8*)(xb + kk * 32 + quad * 8);
      }
      f32x4 acc[4];
#pragma unroll
      for (int mt = 0; mt < 4; mt++) acc[mt] = (f32x4){0.f, 0.f, 0.f, 0.f};
#pragma unroll
      for (int kk = 0; kk < 8; kk++)
#pragma unroll
        for (int mt = 0; mt < 4; mt++)
          acc[mt] = __builtin_amdgcn_mfma_f32_16x16x32_bf16(w[mt][kk], bfr[kk], acc[mt], 0, 0, 0);
      if (em) {
        unsigned short* ep = xs + ((size_t)t2 * B_ + b0 + lm) * X_ + quad * 8;
        U8 e0, e1;
        e0.v = (wv == 0) ? bfr[0] : (wv == 1) ? bfr[2] : (wv == 2) ? bfr[4] : bfr[6];
        e1.v = (wv == 0) ? bfr[1] : (wv == 1) ? bfr[3] : (wv == 2) ? bfr[5] : bfr[7];
        *(uint4*)(ep + (2 * wv) * 32)     = e0.q;
        *(uint4*)(ep + (2 * wv + 1) * 32) = e1.q;
      }
      {
        unsigned short* xn = &Xb[1][1 - p2][0] + lm * 264 + wv * 64 + quad * 4;
#pragma unroll
        for (int mt = 0; mt < 4; mt++) {
          unsigned int lo = d2[mt].x, hi = d2[mt].y;
          float f0 = bf2f((unsigned short)(lo & 0xffff));
          float f1 = bf2f((unsigned short)(lo >> 16));
          float f2 = bf2f((unsigned short)(hi & 0xffff));
          float f3 = bf2f((unsigned short)(hi >> 16));
          uint2 ov;
          ov.x = pack2(acc[mt][0] + f0, acc[mt][1] + f1);
          ov.y = pack2(acc[mt][2] + f2, acc[mt][3] + f3);
          *(uint2*)(xn + mt * 16) = ov;
        }
      }
#pragma unroll
      for (int mt = 0; mt < 4; mt++) d2[mt] = dn[mt];
      t2++; p2 ^= 1;
    }

    bar_lds();
  }
}

// ---------------------------------------------------------------------------
// Kernel 4 v6: weight-stationary heads, spill-proof (measured clean in r6).
// ---------------------------------------------------------------------------
__global__ __launch_bounds__(512, 4) void heads_kernel(
    const unsigned short* __restrict__ xs, const unsigned short* __restrict__ wb,
    const float* __restrict__ by1, const float* __restrict__ by2,
    const float* __restrict__ bz1, const float* __restrict__ bz2,
    float* __restrict__ yout, float* __restrict__ zout) {
  __shared__ __align__(16) unsigned short sbuf[64 * 264];   // xt, then ht
  __shared__ __align__(16) unsigned short w2s[64 * 264];    // W2 rows (64 or 16)
  const int tid  = threadIdx.x;
  const int head = blockIdx.x & 1;
  const int t0   = (blockIdx.x >> 1) * HEADS_TCH;

  const int wv = tid >> 6, lane = tid & 63, lm = lane & 15, quad = lane >> 4;
  const unsigned short* w1 = wb + (head ? 81920  : 0);
  const unsigned short* w2 = wb + (head ? 147456 : 65536);
  const float* b1p = head ? bz1 : by1;
  const float* b2p = head ? bz2 : by2;

  // ---- stage W2 into LDS once per block (covered by first P0 barrier) ----
  {
    const int nrow = head ? 16 : 64;
    for (int ch = tid; ch < nrow * 32; ch += 512) {
      int row = ch >> 5, col = (ch & 31) * 8;
      *(uint4*)(w2s + row * 264 + col) = *(const uint4*)(w2 + (size_t)row * 256 + col);
    }
  }

  // ---- W1 fragments, loaded ONCE per block (wave owns n-cols [wv*32,+32)) ----
  bf16x8 w1f[2][8];
  float  bias1[2];
#pragma unroll
  for (int nt = 0; nt < 2; nt++) {
    int n = wv * 32 + nt * 16 + lm;
#pragma unroll
    for (int kk = 0; kk < 8; kk++)
      w1f[nt][kk] = *(const bf16x8*)(w1 + (size_t)n * 256 + kk * 32 + quad * 8);
    bias1[nt] = b1p[n];
  }
  // layer-2 tile assignment: head0: wave -> (ntile = wv&3, mpair = wv>>2);
  // head1: waves 0-3, m-tile = wv.
  const int ntile = head ? 0 : (wv & 3);
  const int mpair = head ? 0 : (wv >> 2);
  float bias2 = 0.f;
  if (head == 0 || wv < 4) bias2 = b2p[ntile * 16 + lm];

  // ---- x stage mapping: 64 rows x 32 uint4-chunks, 4 chunks/thread ----
  const int srow = tid >> 5;          // 0..15 (+ c*16)
  const int scol = (tid & 31) * 8;    // bf16 col

  for (int j = 0; j < HEADS_TCH; j++) {
    const int t = t0 + j;

    // P0: direct global -> LDS stage of x_t (short-lived temps, NO
    // loop-carried prefetch state -> nothing for the allocator to spill)
    {
      uint4 x0 = *(const uint4*)(xs + ((size_t)t * 64 + srow +  0) * 256 + scol);
      uint4 x1 = *(const uint4*)(xs + ((size_t)t * 64 + srow + 16) * 256 + scol);
      uint4 x2 = *(const uint4*)(xs + ((size_t)t * 64 + srow + 32) * 256 + scol);
      uint4 x3 = *(const uint4*)(xs + ((size_t)t * 64 + srow + 48) * 256 + scol);
      *(uint4*)(sbuf + (srow +  0) * 264 + scol) = x0;
      *(uint4*)(sbuf + (srow + 16) * 264 + scol) = x1;
      *(uint4*)(sbuf + (srow + 32) * 264 + scol) = x2;
      *(uint4*)(sbuf + (srow + 48) * 264 + scol) = x3;
    }
    bar_lds();

    // P1: layer 1  h = x @ W1^T (wave's 32 n-cols, all 64 rows), kk-outer:
    // 8 independent acc targets per kk -> no dependent-MFMA chains.
    f32x4 acc[2][4];   // [nt][m]
#pragma unroll
    for (int nt = 0; nt < 2; nt++)
#pragma unroll
      for (int m = 0; m < 4; m++) acc[nt][m] = (f32x4){0.f, 0.f, 0.f, 0.f};

#pragma unroll
    for (int kk = 0; kk < 8; kk++) {
      bf16x8 af[4];
#pragma unroll
      for (int m = 0; m < 4; m++)
        af[m] = *(const bf16x8*)(sbuf + (m * 16 + lm) * 264 + kk * 32 + quad * 8);
#pragma unroll
      for (int nt = 0; nt < 2; nt++)
#pragma unroll
        for (int m = 0; m < 4; m++)
          acc[nt][m] = __builtin_amdgcn_mfma_f32_16x16x32_bf16(af[m], w1f[nt][kk], acc[nt][m], 0, 0, 0);
    }
    bar_lds();   // all waves done READING xt -> safe to overwrite with h

    // P2: epilogue bias+relu -> sbuf (now ht)
#pragma unroll
    for (int nt = 0; nt < 2; nt++) {
      int n = wv * 32 + nt * 16 + lm;
#pragma unroll
      for (int m = 0; m < 4; m++)
#pragma unroll
        for (int rg = 0; rg < 4; rg++) {
          float v = fmaxf(acc[nt][m][rg] + bias1[nt], 0.f);
          sbuf[(m * 16 + quad * 4 + rg) * 264 + n] = f2bf(v);
        }
    }
    bar_lds();   // layer2 reads all cols of ht

    // P3: layer 2 + sigmoid + store (W2 fragments read from LDS)
    if (head == 0) {       // N=64: wave -> n-tile (wv&3), m-tiles {2*mpair,2*mpair+1}
      f32x4 a2[2];
#pragma unroll
      for (int mm = 0; mm < 2; mm++) a2[mm] = (f32x4){0.f, 0.f, 0.f, 0.f};
#pragma unroll
      for (int kk = 0; kk < 8; kk++) {
        bf16x8 b = *(const bf16x8*)(w2s + (ntile * 16 + lm) * 264 + kk * 32 + quad * 8);
#pragma unroll
        for (int mm = 0; mm < 2; mm++) {
          int m = mpair * 2 + mm;
          bf16x8 a = *(const bf16x8*)(sbuf + (m * 16 + lm) * 264 + kk * 32 + quad * 8);
          a2[mm] = __builtin_amdgcn_mfma_f32_16x16x32_bf16(a, b, a2[mm], 0, 0, 0);
        }
      }
      int n = ntile * 16 + lm;
#pragma unroll
      for (int mm = 0; mm < 2; mm++)
#pragma unroll
        for (int rg = 0; rg < 4; rg++) {
          int bb = (mpair * 2 + mm) * 16 + quad * 4 + rg;
          float v = a2[mm][rg] + bias2;
          v = 1.f / (1.f + __expf(-v));
          yout[((size_t)bb * T_ + t) * 64 + n] = v;
        }
    } else if (wv < 4) {   // N=16: waves 0-3 take m-tile = wv
      f32x4 a2 = (f32x4){0.f, 0.f, 0.f, 0.f};
#pragma unroll
      for (int kk = 0; kk < 8; kk++) {
        bf16x8 b = *(const bf16x8*)(w2s + lm * 264 + kk * 32 + quad * 8);
        bf16x8 a = *(const bf16x8*)(sbuf + (wv * 16 + lm) * 264 + kk * 32 + quad * 8);
        a2 = __builtin_amdgcn_mfma_f32_16x16x32_bf16(a, b, a2, 0, 0, 0);
      }
#pragma unroll
      for (int rg = 0; rg < 4; rg++) {
        int bb = wv * 16 + quad * 4 + rg;
        float v = a2[rg] + bias2;
        v = 1.f / (1.f + __expf(-v));
        zout[((size_t)bb * T_ + t) * 16 + lm] = v;
      }
    }
    bar_lds();   // h reads done -> next P0 may overwrite sbuf
  }
}

// ---------------------------------------------------------------------------
extern "C" void kernel_launch(void* const* d_in, const int* in_sizes, int n_in,
                              void* d_out, int out_size, void* d_ws, size_t ws_size,
                              hipStream_t stream) {
  const float* y    = (const float*)d_in[0];
  const float* u    = (const float*)d_in[1];
  const float* Aw   = (const float*)d_in[2];
  const float* Ab   = (const float*)d_in[3];
  const float* Kw   = (const float*)d_in[4];
  const float* Kb   = (const float*)d_in[5];
  const float* Bw   = (const float*)d_in[6];
  const float* Bb   = (const float*)d_in[7];
  const float* Cy1w = (const float*)d_in[8];
  const float* Cy1b = (const float*)d_in[9];
  const float* Cy2w = (const float*)d_in[10];
  const float* Cy2b = (const float*)d_in[11];
  const float* Cz1w = (const float*)d_in[12];
  const float* Cz1b = (const float*)d_in[13];
  const float* Cz2w = (const float*)d_in[14];
  const float* Cz2b = (const float*)d_in[15];

  // ws layout (bf16 unless noted):
  //   drv [T*B*X] | xs [T*B*X] | wb [151552] | wcat [24576] | bsum fp32 [256]
  unsigned short* drv  = (unsigned short*)d_ws;
  unsigned short* xs   = drv + (size_t)T_ * B_ * X_;
  unsigned short* wb   = xs  + (size_t)T_ * B_ * X_;
  unsigned short* wcat = wb + 151552;
  float*          bsum = (float*)(wcat + 24576);

  float* yout = (float*)d_out;
  float* zout = yout + (size_t)B_ * T_ * 64;

  hipLaunchKernelGGL(conv_kernel, dim3(688), dim3(256), 0, stream,
                     Cy1w, Cy2w, Cz1w, Cz2w, Kw, Bw, Kb, Bb, Ab, wb, wcat, bsum);
  hipLaunchKernelGGL(drive_kernel, dim3(T_ / DRIVE_TCH), dim3(512), 0, stream,
                     y, u, wcat, bsum, drv);
  hipLaunchKernelGGL(scan_kernel, dim3((T_ / SCAN_L) * 2), dim3(256), 0, stream,
                     drv, Aw, xs);
  hipLaunchKernelGGL(heads_kernel, dim3(2 * (T_ / HEADS_TCH)), dim3(512), 0, stream,
                     xs, wb, Cy1b, Cy2b, Cz1b, Cz2b, yout, zout);
}

// Round 12
// 254.679 us; speedup vs baseline: 1.0706x; 1.0224x over previous
//
#include <hip/hip_runtime.h>

// Problem constants
#define B_  64
#define T_  2048
#define X_  256

// scan chunking: emit length L and warmup W (||A^16|| ~ 3e-4 << bf16 noise)
#define SCAN_L 16
#define SCAN_W 16

// heads: timesteps per merged-heads block (grid = T_/HEADS_TCH)
#define HEADS_TCH 8
// drive: timesteps per persistent block (grid = T_/DRIVE_TCH)
#define DRIVE_TCH 4

typedef __bf16 bf16x8 __attribute__((ext_vector_type(8)));
typedef float  f32x4  __attribute__((ext_vector_type(4)));

__device__ __forceinline__ unsigned short f2bf(float v) {
  unsigned int x = __float_as_uint(v);
  x += 0x7fffu + ((x >> 16) & 1u);   // RNE
  return (unsigned short)(x >> 16);
}
__device__ __forceinline__ float bf2f(unsigned short s) {
  return __uint_as_float(((unsigned int)s) << 16);
}
__device__ __forceinline__ unsigned int pack2(float a, float b) {
  return (unsigned int)f2bf(a) | ((unsigned int)f2bf(b) << 16);
}

// LDS-only barrier: waits lgkm only (no vmcnt(0) drain of in-flight global
// ops at every barrier; global loads are register-consumed with counted
// vmcnt at the use).
__device__ __forceinline__ void bar_lds() {
  asm volatile("s_waitcnt lgkmcnt(0)\n\ts_barrier" ::: "memory");
}

// ---------------------------------------------------------------------------
// Kernel 1 (merged): head weights fp32->bf16 (blocks 0..591) and
// wcat[256][96]=[K_w|Bm_w] bf16 + bsum=K_b+Bm_b+A_b (blocks 592..687).
// ---------------------------------------------------------------------------
__global__ __launch_bounds__(256) void conv_kernel(
    const float* __restrict__ cy1, const float* __restrict__ cy2,
    const float* __restrict__ cz1, const float* __restrict__ cz2,
    const float* __restrict__ Kw, const float* __restrict__ Bw,
    const float* __restrict__ Kb, const float* __restrict__ Bb,
    const float* __restrict__ Ab,
    unsigned short* __restrict__ wb,
    unsigned short* __restrict__ wcat, float* __restrict__ bsum) {
  if (blockIdx.x < 592) {
    int i = blockIdx.x * 256 + threadIdx.x;
    if (i < 65536)        wb[i] = f2bf(cy1[i]);
    else if (i < 81920)   wb[i] = f2bf(cy2[i - 65536]);
    else if (i < 147456)  wb[i] = f2bf(cz1[i - 81920]);
    else if (i < 151552)  wb[i] = f2bf(cz2[i - 147456]);
  } else {
    int k = blockIdx.x - 592;   // 0..95
    int x = threadIdx.x;        // 0..255
    float v = (k < 64) ? Kw[x * 64 + k] : Bw[x * 32 + (k - 64)];
    wcat[x * 96 + k] = f2bf(v);
    if (k == 0) bsum[x] = Kb[x] + Bb[x] + Ab[x];
  }
}

// ---------------------------------------------------------------------------
// Kernel 2 v2: weight-stationary drive (measured clean in r8).
// ---------------------------------------------------------------------------
__global__ __launch_bounds__(512, 4) void drive_kernel(
    const float* __restrict__ y, const float* __restrict__ u,
    const unsigned short* __restrict__ wcat, const float* __restrict__ bsum,
    unsigned short* __restrict__ drv) {
  __shared__ __align__(16) unsigned short cat[64 * 104];  // 96 + 8 pad
  __shared__ __align__(16) unsigned short ot[64 * 264];
  const int tid = threadIdx.x;
  const int t0  = blockIdx.x * DRIVE_TCH;
  const int wv = tid >> 6, lane = tid & 63, lm = lane & 15, quad = lane >> 4;

  // weight fragments: wave owns n-cols [wv*32, wv*32+32), loaded once
  bf16x8 bf[2][3];
  float  bias[2];
#pragma unroll
  for (int nt = 0; nt < 2; nt++) {
    int n = wv * 32 + nt * 16 + lm;
#pragma unroll
    for (int kk = 0; kk < 3; kk++)
      bf[nt][kk] = *(const bf16x8*)(wcat + (size_t)n * 96 + kk * 32 + quad * 8);
    bias[nt] = bsum[n];
  }

  for (int j = 0; j < DRIVE_TCH; j++) {
    const int t = t0 + j;

    // stage y: 64 rows x 16 float4 chunks = 1024 (2 per thread)
#pragma unroll
    for (int it = 0; it < 2; it++) {
      int ch = it * 512 + tid;
      int row = ch >> 4, c4 = (ch & 15) * 4;
      float4 v = *(const float4*)(y + ((size_t)row * T_ + t) * 64 + c4);
      uint2 pv; pv.x = pack2(v.x, v.y); pv.y = pack2(v.z, v.w);
      *(uint2*)(cat + row * 104 + c4) = pv;
    }
    // stage u: 64 rows x 8 float4 chunks = 512 (1 per thread)
    {
      int ch = tid;
      int row = ch >> 3, c4 = (ch & 7) * 4;
      float4 v = *(const float4*)(u + ((size_t)row * T_ + t) * 32 + c4);
      uint2 pv; pv.x = pack2(v.x, v.y); pv.y = pack2(v.z, v.w);
      *(uint2*)(cat + row * 104 + 64 + c4) = pv;
    }
    bar_lds();   // cat ready; also guards ot reuse (store of t-1 read pre-bar)

    f32x4 acc[2][4];   // [nt][m]
#pragma unroll
    for (int nt = 0; nt < 2; nt++)
#pragma unroll
      for (int m = 0; m < 4; m++) acc[nt][m] = (f32x4){0.f, 0.f, 0.f, 0.f};

#pragma unroll
    for (int m = 0; m < 4; m++) {
      bf16x8 af[3];
#pragma unroll
      for (int kk = 0; kk < 3; kk++)
        af[kk] = *(const bf16x8*)(cat + (m * 16 + lm) * 104 + kk * 32 + quad * 8);
#pragma unroll
      for (int kk = 0; kk < 3; kk++)
#pragma unroll
        for (int nt = 0; nt < 2; nt++)
          acc[nt][m] = __builtin_amdgcn_mfma_f32_16x16x32_bf16(af[kk], bf[nt][kk], acc[nt][m], 0, 0, 0);
    }

    // epilogue: bias -> ot (wave writes its own 32 cols)
#pragma unroll
    for (int nt = 0; nt < 2; nt++) {
      int n = wv * 32 + nt * 16 + lm;
#pragma unroll
      for (int m = 0; m < 4; m++)
#pragma unroll
        for (int rg = 0; rg < 4; rg++)
          ot[(m * 16 + quad * 4 + rg) * 264 + n] = f2bf(acc[nt][m][rg] + bias[nt]);
    }
    bar_lds();   // all cat reads + ot writes done

    // store ot -> drv (coalesced): 64 rows x 32 uint4 chunks = 2048 (4/thread)
#pragma unroll
    for (int it = 0; it < 4; it++) {
      int ch = it * 512 + tid, row = ch >> 5, col = (ch & 31) * 8;
      uint4 v = *(const uint4*)(ot + row * 264 + col);
      *(uint4*)(drv + ((size_t)t * B_ + row) * X_ + col) = v;
    }
    // next iteration's stage-bar covers ot-read completion before epi rewrite
  }
}

// ---------------------------------------------------------------------------
// Kernel 3 v5: dual-chain interleaved scan (measured clean in r11: dropped
// out of top-5, <70 us; fat-register regime, spill-proof).
// ---------------------------------------------------------------------------
__global__ __launch_bounds__(256, 1) void scan_kernel(
    const unsigned short* __restrict__ drv,   // d' = drive + A_b
    const float* __restrict__ Aw,
    unsigned short* __restrict__ xs) {
  __shared__ __align__(16) unsigned short Xb[2][2][16 * 264];  // [chain][pingpong]
  const int tid = threadIdx.x;
  const int wv = tid >> 6, lane = tid & 63, lm = lane & 15, quad = lane >> 4;
  const int pr = blockIdx.x >> 2;                 // pair 0..63
  const int b0 = (blockIdx.x & 3) * 16;
  const int c1 = pr;                              // chunk 0..63
  const int c2 = pr + (T_ / SCAN_L / 2);          // chunk 64..127

  union U8 { bf16x8 v; unsigned short u[8]; uint4 q; };
  bf16x8 w[4][8];   // wave owns A-rows [wv*64, wv*64+64), shared by chains
#pragma unroll
  for (int mt = 0; mt < 4; mt++) {
#pragma unroll
    for (int kk = 0; kk < 8; kk++) {
      const float* p = Aw + (size_t)((wv * 4 + mt) * 16 + lm) * 256 + kk * 32 + quad * 8;
      float4 a = *(const float4*)p;
      float4 b = *(const float4*)(p + 4);
      U8 tmp;
      tmp.u[0] = f2bf(a.x); tmp.u[1] = f2bf(a.y); tmp.u[2] = f2bf(a.z); tmp.u[3] = f2bf(a.w);
      tmp.u[4] = f2bf(b.x); tmp.u[5] = f2bf(b.y); tmp.u[6] = f2bf(b.z); tmp.u[7] = f2bf(b.w);
      w[mt][kk] = tmp.v;
    }
  }

  {  // zero all state buffers
    unsigned int* xz = (unsigned int*)&Xb[0][0][0];
    for (int i = tid; i < (2 * 2 * 16 * 264) / 2; i += 256) xz[i] = 0u;
  }
  bar_lds();

  int t1 = (c1 == 0) ? 0 : (c1 * SCAN_L - SCAN_W);
  int t2 = c2 * SCAN_L - SCAN_W;

  uint2 d1[4], d2[4];
  {
    const unsigned short* dp = drv + ((size_t)t1 * B_ + b0 + lm) * X_ + wv * 64 + quad * 4;
#pragma unroll
    for (int mt = 0; mt < 4; mt++) d1[mt] = *(const uint2*)(dp + mt * 16);
  }
  {
    const unsigned short* dp = drv + ((size_t)t2 * B_ + b0 + lm) * X_ + wv * 64 + quad * 4;
#pragma unroll
    for (int mt = 0; mt < 4; mt++) d2[mt] = *(const uint2*)(dp + mt * 16);
  }

  int p1 = 0, p2 = 0;
  for (int j = 0; j < SCAN_W + SCAN_L; j++) {
    const bool act1 = (c1 > 0) || (j >= SCAN_W);  // c1==0 has no warmup
    const bool em   = (j >= SCAN_W);

    // ---------------- chain 1 ----------------
    if (act1) {
      uint2 dn[4];
      {
        int tn = (t1 + 1 < T_) ? t1 + 1 : T_ - 1;
        const unsigned short* dp = drv + ((size_t)tn * B_ + b0 + lm) * X_ + wv * 64 + quad * 4;
#pragma unroll
        for (int mt = 0; mt < 4; mt++) dn[mt] = *(const uint2*)(dp + mt * 16);
      }
      bf16x8 bfr[8];
      {
        const unsigned short* xb = &Xb[0][p1][0] + lm * 264;
#pragma unroll
        for (int kk = 0; kk < 8; kk++)
          bfr[kk] = *(const bf16x8*)(xb + kk * 32 + quad * 8);
      }
      f32x4 acc[4];
#pragma unroll
      for (int mt = 0; mt < 4; mt++) acc[mt] = (f32x4){0.f, 0.f, 0.f, 0.f};
#pragma unroll
      for (int kk = 0; kk < 8; kk++)
#pragma unroll
        for (int mt = 0; mt < 4; mt++)
          acc[mt] = __builtin_amdgcn_mfma_f32_16x16x32_bf16(w[mt][kk], bfr[kk], acc[mt], 0, 0, 0);
      if (em) {   // immediate emit of pre-update x_t (bfr is live anyway)
        unsigned short* ep = xs + ((size_t)t1 * B_ + b0 + lm) * X_ + quad * 8;
        U8 e0, e1;
        e0.v = (wv == 0) ? bfr[0] : (wv == 1) ? bfr[2] : (wv == 2) ? bfr[4] : bfr[6];
        e1.v = (wv == 0) ? bfr[1] : (wv == 1) ? bfr[3] : (wv == 2) ? bfr[5] : bfr[7];
        *(uint4*)(ep + (2 * wv) * 32)     = e0.q;
        *(uint4*)(ep + (2 * wv + 1) * 32) = e1.q;
      }
      {
        unsigned short* xn = &Xb[0][1 - p1][0] + lm * 264 + wv * 64 + quad * 4;
#pragma unroll
        for (int mt = 0; mt < 4; mt++) {
          unsigned int lo = d1[mt].x, hi = d1[mt].y;
          float f0 = bf2f((unsigned short)(lo & 0xffff));
          float f1 = bf2f((unsigned short)(lo >> 16));
          float f2 = bf2f((unsigned short)(hi & 0xffff));
          float f3 = bf2f((unsigned short)(hi >> 16));
          uint2 ov;
          ov.x = pack2(acc[mt][0] + f0, acc[mt][1] + f1);
          ov.y = pack2(acc[mt][2] + f2, acc[mt][3] + f3);
          *(uint2*)(xn + mt * 16) = ov;
        }
      }
#pragma unroll
      for (int mt = 0; mt < 4; mt++) d1[mt] = dn[mt];
      t1++; p1 ^= 1;
    }

    // ---------------- chain 2 (always active) ----------------
    {
      uint2 dn[4];
      {
        int tn = (t2 + 1 < T_) ? t2 + 1 : T_ - 1;
        const unsigned short* dp = drv + ((size_t)tn * B_ + b0 + lm) * X_ + wv * 64 + quad * 4;
#pragma unroll
        for (int mt = 0; mt < 4; mt++) dn[mt] = *(const uint2*)(dp + mt * 16);
      }
      bf16x8 bfr[8];
      {
        const unsigned short* xb = &Xb[1][p2][0] + lm * 264;
#pragma unroll
        for (int kk = 0; kk < 8; kk++)
          bfr[kk] = *(const bf16x8*)(xb + kk * 32 + quad * 8);
      }
      f32x4 acc[4];
#pragma unroll
      for (int mt = 0; mt < 4; mt++) acc[mt] = (f32x4){0.f, 0.f, 0.f, 0.f};
#pragma unroll
      for (int kk = 0; kk < 8; kk++)
#pragma unroll
        for (int mt = 0; mt < 4; mt++)
          acc[mt] = __builtin_amdgcn_mfma_f32_16x16x32_bf16(w[mt][kk], bfr[kk], acc[mt], 0, 0, 0);
      if (em) {
        unsigned short* ep = xs + ((size_t)t2 * B_ + b0 + lm) * X_ + quad * 8;
        U8 e0, e1;
        e0.v = (wv == 0) ? bfr[0] : (wv == 1) ? bfr[2] : (wv == 2) ? bfr[4] : bfr[6];
        e1.v = (wv == 0) ? bfr[1] : (wv == 1) ? bfr[3] : (wv == 2) ? bfr[5] : bfr[7];
        *(uint4*)(ep + (2 * wv) * 32)     = e0.q;
        *(uint4*)(ep + (2 * wv + 1) * 32) = e1.q;
      }
      {
        unsigned short* xn = &Xb[1][1 - p2][0] + lm * 264 + wv * 64 + quad * 4;
#pragma unroll
        for (int mt = 0; mt < 4; mt++) {
          unsigned int lo = d2[mt].x, hi = d2[mt].y;
          float f0 = bf2f((unsigned short)(lo & 0xffff));
          float f1 = bf2f((unsigned short)(lo >> 16));
          float f2 = bf2f((unsigned short)(hi & 0xffff));
          float f3 = bf2f((unsigned short)(hi >> 16));
          uint2 ov;
          ov.x = pack2(acc[mt][0] + f0, acc[mt][1] + f1);
          ov.y = pack2(acc[mt][2] + f2, acc[mt][3] + f3);
          *(uint2*)(xn + mt * 16) = ov;
        }
      }
#pragma unroll
      for (int mt = 0; mt < 4; mt++) d2[mt] = dn[mt];
      t2++; p2 ^= 1;
    }

    bar_lds();
  }
}

// ---------------------------------------------------------------------------
// Kernel 4 v7: merged-heads dual-ILP block (scan-v5 pattern applied to heads).
//   r11: heads is #1 at 70us (MfmaUtil 22%, 2.1TB/s, occ 33%) -- latency-
//   bound with xs read twice (once per head) and 8 barriers per t-pair.
//   v7: one 512-thread block computes BOTH heads for its 8 timesteps:
//   - x staged ONCE per t, shared by both heads' layer1 (xs fetch halves;
//     each af fragment read feeds 16 MFMAs instead of 8).
//   - 4 barriers per t total (was 4 per head-block = 8).
//   - W1 of both heads register-stationary: 128 VGPR + 64 AGPR acc + temps
//     ~220 unified -> fat regime, __launch_bounds__(512,1): no cap below
//     demand -> NO SPILL POSSIBLE (the five-spill lesson).
//   - LDS: xy/hY 33.8K + hZ 33.8K + W2Y 33.8K + W2Z 8.4K = 110KB, 1 blk/CU,
//     grid 256 = exactly 1/CU.
//   Per-element arithmetic (kk-ascending layer1, v6 epilogue/layer2) is
//   byte-identical -> bit-identical outputs.
//   Falsifier: WRITE >> 56MB = spill -> revert; clean but dur >= 70 ->
//   TLP loss dominated -> revert and dual-ILP drive instead.
// ---------------------------------------------------------------------------
__global__ __launch_bounds__(512, 1) void heads_kernel(
    const unsigned short* __restrict__ xs, const unsigned short* __restrict__ wb,
    const float* __restrict__ by1, const float* __restrict__ by2,
    const float* __restrict__ bz1, const float* __restrict__ bz2,
    float* __restrict__ yout, float* __restrict__ zout) {
  __shared__ __align__(16) unsigned short sbuf[64 * 264];   // xt, then hY
  __shared__ __align__(16) unsigned short hzb[64 * 264];    // hZ
  __shared__ __align__(16) unsigned short w2sy[64 * 264];   // W2 y-head
  __shared__ __align__(16) unsigned short w2sz[16 * 264];   // W2 z-head
  const int tid = threadIdx.x;
  const int t0  = blockIdx.x * HEADS_TCH;

  const int wv = tid >> 6, lane = tid & 63, lm = lane & 15, quad = lane >> 4;
  const unsigned short* w1y = wb;             // Cy1 256x256
  const unsigned short* w2y = wb + 65536;     // Cy2 64x256
  const unsigned short* w1z = wb + 81920;     // Cz1 256x256
  const unsigned short* w2z = wb + 147456;    // Cz2 16x256

  // ---- stage W2 (both heads) into LDS once (covered by first P0 barrier) ----
  for (int ch = tid; ch < 64 * 32; ch += 512) {
    int row = ch >> 5, col = (ch & 31) * 8;
    *(uint4*)(w2sy + row * 264 + col) = *(const uint4*)(w2y + (size_t)row * 256 + col);
  }
  for (int ch = tid; ch < 16 * 32; ch += 512) {
    int row = ch >> 5, col = (ch & 31) * 8;
    *(uint4*)(w2sz + row * 264 + col) = *(const uint4*)(w2z + (size_t)row * 256 + col);
  }

  // ---- W1 fragments (both heads), loaded ONCE (wave owns n-cols [wv*32,+32)) ----
  bf16x8 w1fY[2][8], w1fZ[2][8];
  float  b1Y[2], b1Z[2];
#pragma unroll
  for (int nt = 0; nt < 2; nt++) {
    int n = wv * 32 + nt * 16 + lm;
#pragma unroll
    for (int kk = 0; kk < 8; kk++) {
      w1fY[nt][kk] = *(const bf16x8*)(w1y + (size_t)n * 256 + kk * 32 + quad * 8);
      w1fZ[nt][kk] = *(const bf16x8*)(w1z + (size_t)n * 256 + kk * 32 + quad * 8);
    }
    b1Y[nt] = by1[n];
    b1Z[nt] = bz1[n];
  }
  // layer-2 tile assignment (v6 mapping): y-head: all 8 waves, ntile=wv&3,
  // mpair=wv>>2; z-head: waves 0-3, m-tile=wv.
  const int ntile = wv & 3;
  const int mpair = wv >> 2;
  const float b2Y = by2[ntile * 16 + lm];
  const float b2Z = (wv < 4) ? bz2[lm] : 0.f;

  // ---- x stage mapping: 64 rows x 32 uint4-chunks, 4 chunks/thread ----
  const int srow = tid >> 5;          // 0..15 (+ c*16)
  const int scol = (tid & 31) * 8;    // bf16 col

  for (int j = 0; j < HEADS_TCH; j++) {
    const int t = t0 + j;

    // P0: direct global -> LDS stage of x_t (short-lived temps only)
    {
      uint4 x0 = *(const uint4*)(xs + ((size_t)t * 64 + srow +  0) * 256 + scol);
      uint4 x1 = *(const uint4*)(xs + ((size_t)t * 64 + srow + 16) * 256 + scol);
      uint4 x2 = *(const uint4*)(xs + ((size_t)t * 64 + srow + 32) * 256 + scol);
      uint4 x3 = *(const uint4*)(xs + ((size_t)t * 64 + srow + 48) * 256 + scol);
      *(uint4*)(sbuf + (srow +  0) * 264 + scol) = x0;
      *(uint4*)(sbuf + (srow + 16) * 264 + scol) = x1;
      *(uint4*)(sbuf + (srow + 32) * 264 + scol) = x2;
      *(uint4*)(sbuf + (srow + 48) * 264 + scol) = x3;
    }
    bar_lds();

    // P1: layer 1 BOTH heads, kk-outer; af fragments shared across heads
    // (4 ds_reads feed 16 MFMAs per kk).
    f32x4 accY[2][4], accZ[2][4];   // [nt][m]
#pragma unroll
    for (int nt = 0; nt < 2; nt++)
#pragma unroll
      for (int m = 0; m < 4; m++) {
        accY[nt][m] = (f32x4){0.f, 0.f, 0.f, 0.f};
        accZ[nt][m] = (f32x4){0.f, 0.f, 0.f, 0.f};
      }

#pragma unroll
    for (int kk = 0; kk < 8; kk++) {
      bf16x8 af[4];
#pragma unroll
      for (int m = 0; m < 4; m++)
        af[m] = *(const bf16x8*)(sbuf + (m * 16 + lm) * 264 + kk * 32 + quad * 8);
#pragma unroll
      for (int nt = 0; nt < 2; nt++)
#pragma unroll
        for (int m = 0; m < 4; m++) {
          accY[nt][m] = __builtin_amdgcn_mfma_f32_16x16x32_bf16(af[m], w1fY[nt][kk], accY[nt][m], 0, 0, 0);
          accZ[nt][m] = __builtin_amdgcn_mfma_f32_16x16x32_bf16(af[m], w1fZ[nt][kk], accZ[nt][m], 0, 0, 0);
        }
    }
    bar_lds();   // all waves done READING xt -> safe to overwrite with hY

    // P2: epilogue bias+relu: hY -> sbuf (overwrites x), hZ -> hzb
#pragma unroll
    for (int nt = 0; nt < 2; nt++) {
      int n = wv * 32 + nt * 16 + lm;
#pragma unroll
      for (int m = 0; m < 4; m++)
#pragma unroll
        for (int rg = 0; rg < 4; rg++) {
          int row = m * 16 + quad * 4 + rg;
          float vy = fmaxf(accY[nt][m][rg] + b1Y[nt], 0.f);
          float vz = fmaxf(accZ[nt][m][rg] + b1Z[nt], 0.f);
          sbuf[row * 264 + n] = f2bf(vy);
          hzb[row * 264 + n]  = f2bf(vz);
        }
    }
    bar_lds();   // layer2 reads all cols of hY/hZ

    // P3: layer 2 + sigmoid + store (both heads)
    {   // y-head, N=64: wave -> n-tile (wv&3), m-tiles {2*mpair, 2*mpair+1}
      f32x4 a2[2];
#pragma unroll
      for (int mm = 0; mm < 2; mm++) a2[mm] = (f32x4){0.f, 0.f, 0.f, 0.f};
#pragma unroll
      for (int kk = 0; kk < 8; kk++) {
        bf16x8 b = *(const bf16x8*)(w2sy + (ntile * 16 + lm) * 264 + kk * 32 + quad * 8);
#pragma unroll
        for (int mm = 0; mm < 2; mm++) {
          int m = mpair * 2 + mm;
          bf16x8 a = *(const bf16x8*)(sbuf + (m * 16 + lm) * 264 + kk * 32 + quad * 8);
          a2[mm] = __builtin_amdgcn_mfma_f32_16x16x32_bf16(a, b, a2[mm], 0, 0, 0);
        }
      }
      int n = ntile * 16 + lm;
#pragma unroll
      for (int mm = 0; mm < 2; mm++)
#pragma unroll
        for (int rg = 0; rg < 4; rg++) {
          int bb = (mpair * 2 + mm) * 16 + quad * 4 + rg;
          float v = a2[mm][rg] + b2Y;
          v = 1.f / (1.f + __expf(-v));
          yout[((size_t)bb * T_ + t) * 64 + n] = v;
        }
    }
    if (wv < 4) {   // z-head, N=16: waves 0-3 take m-tile = wv
      f32x4 a2 = (f32x4){0.f, 0.f, 0.f, 0.f};
#pragma unroll
      for (int kk = 0; kk < 8; kk++) {
        bf16x8 b = *(const bf16x8*)(w2sz + lm * 264 + kk * 32 + quad * 8);
        bf16x8 a = *(const bf16x8*)(hzb + (wv * 16 + lm) * 264 + kk * 32 + quad * 8);
        a2 = __builtin_amdgcn_mfma_f32_16x16x32_bf16(a, b, a2, 0, 0, 0);
      }
#pragma unroll
      for (int rg = 0; rg < 4; rg++) {
        int bb = wv * 16 + quad * 4 + rg;
        float v = a2[rg] + b2Z;
        v = 1.f / (1.f + __expf(-v));
        zout[((size_t)bb * T_ + t) * 16 + lm] = v;
      }
    }
    bar_lds();   // h reads done -> next P0 may overwrite sbuf
  }
}

// ---------------------------------------------------------------------------
extern "C" void kernel_launch(void* const* d_in, const int* in_sizes, int n_in,
                              void* d_out, int out_size, void* d_ws, size_t ws_size,
                              hipStream_t stream) {
  const float* y    = (const float*)d_in[0];
  const float* u    = (const float*)d_in[1];
  const float* Aw   = (const float*)d_in[2];
  const float* Ab   = (const float*)d_in[3];
  const float* Kw   = (const float*)d_in[4];
  const float* Kb   = (const float*)d_in[5];
  const float* Bw   = (const float*)d_in[6];
  const float* Bb   = (const float*)d_in[7];
  const float* Cy1w = (const float*)d_in[8];
  const float* Cy1b = (const float*)d_in[9];
  const float* Cy2w = (const float*)d_in[10];
  const float* Cy2b = (const float*)d_in[11];
  const float* Cz1w = (const float*)d_in[12];
  const float* Cz1b = (const float*)d_in[13];
  const float* Cz2w = (const float*)d_in[14];
  const float* Cz2b = (const float*)d_in[15];

  // ws layout (bf16 unless noted):
  //   drv [T*B*X] | xs [T*B*X] | wb [151552] | wcat [24576] | bsum fp32 [256]
  unsigned short* drv  = (unsigned short*)d_ws;
  unsigned short* xs   = drv + (size_t)T_ * B_ * X_;
  unsigned short* wb   = xs  + (size_t)T_ * B_ * X_;
  unsigned short* wcat = wb + 151552;
  float*          bsum = (float*)(wcat + 24576);

  float* yout = (float*)d_out;
  float* zout = yout + (size_t)B_ * T_ * 64;

  hipLaunchKernelGGL(conv_kernel, dim3(688), dim3(256), 0, stream,
                     Cy1w, Cy2w, Cz1w, Cz2w, Kw, Bw, Kb, Bb, Ab, wb, wcat, bsum);
  hipLaunchKernelGGL(drive_kernel, dim3(T_ / DRIVE_TCH), dim3(512), 0, stream,
                     y, u, wcat, bsum, drv);
  hipLaunchKernelGGL(scan_kernel, dim3((T_ / SCAN_L) * 2), dim3(256), 0, stream,
                     drv, Aw, xs);
  hipLaunchKernelGGL(heads_kernel, dim3(T_ / HEADS_TCH), dim3(512), 0, stream,
                     xs, wb, Cy1b, Cy2b, Cz1b, Cz2b, yout, zout);
}